// Round 19
// baseline (79.658 us; speedup 1.0000x reference)
//
#include <hip/hip_runtime.h>
#include <math.h>

#define NWAY 5
#define KSHOT 5
#define PRJ 14
#define DD 64
#define PP 100
#define NQ 1024
#define NS 350
#define NPAIR 70
#define LAMDA 32.0f
#define MARGIN 0.3f
#define FGROUPS 25
#define KCH 256

// ---- workspace layout (floats) ----
#define VPTS_OFF  448000     // [350][6400] = 2240000 ([p][d] layout)
#define B2T_OFF   2688000    // bf16 [70][6400]
#define MM_OFF    3136000    // [70][100]
#define VNINV_OFF 3143000    // [70] pad 128
#define PSUM_OFF  3143128    // [70][64]
#define QV_OFF    3147608    // [1024][64]
#define SIM32_OFF 3315544    // [25][1024][70] = 1792000
#define PW_OFF    7903064    // [1024][70]
#define PQ2_OFF   7974744    // [2][1024][5][64] = 655360
#define CLS_OFF   9285464    // [1024]
#define ALN_OFF   9286488    // [1024]
#define PSUMP_OFF 9287512    // [70][25][64]
#define SSQP_OFF  9399512    // [70][25]
#define FQBF_OFF  9401344    // bf16 [1024][6400] = 3276800 floats
#define VPTA_OFF  12678144   // bf16 [5][64][1792] = 286720 floats
#define SG_OFF    12964864   // [1024][5][128] = 655360

#define PQ_ELEMS (NQ*NWAY*64)
#define SIM_STRIDE (NQ*NPAIR)

typedef __attribute__((ext_vector_type(8))) short short8;
typedef __attribute__((ext_vector_type(4))) float f32x4;

__device__ __forceinline__ float redsum64(float x){
  #pragma unroll
  for (int o = 1; o < 64; o <<= 1) x += __shfl_xor(x, o, 64);
  return x;
}

// f32 -> bf16 (RNE) bit pack
__device__ __forceinline__ unsigned short bfr(float x){
  unsigned int u = __float_as_uint(x);
  unsigned int r = (u + 0x7FFFu + ((u >> 16) & 1u)) >> 16;
  return (unsigned short)r;
}

// ---------------- kN: per-sample normalize; support -> vptS, query -> fqb(bf16)+qv ----------------
__global__ __launch_bounds__(256) void kN(const float* __restrict__ feat,
                                          float* __restrict__ vptS,
                                          float* __restrict__ qv,
                                          unsigned short* __restrict__ fqb){
  __shared__ float lds[64*101];
  __shared__ float inv[100];
  int s = blockIdx.x, t = threadIdx.x;
  const float* fp = feat + (size_t)s * 6400;
  #pragma unroll
  for (int i = 0; i < 25; i++){
    int j = t + 256*i;
    int d = j / 100, p = j - d*100;
    lds[d*101 + p] = fp[j];
  }
  __syncthreads();
  if (t < 100){
    float ss = 0.f;
    #pragma unroll
    for (int d = 0; d < 64; d++){ float x = lds[d*101 + t]; ss += x*x; }
    inv[t] = 1.f / fmaxf(sqrtf(ss), 1e-12f);
  }
  __syncthreads();
  if (s < NS){
    #pragma unroll
    for (int i = 0; i < 25; i++){
      int j = t + 256*i;
      int p = j >> 6, d = j & 63;
      vptS[(size_t)s*6400 + j] = lds[d*101 + p] * inv[p];
    }
  } else {
    int q = s - NS;
    #pragma unroll
    for (int i = 0; i < 25; i++){
      int j = t + 256*i;
      int d = j / 100, p = j - d*100;
      fqb[(size_t)q*6400 + j] = bfr(lds[d*101 + p] * inv[p]);
    }
    if (t < 64){
      float sum = 0.f;
      for (int p = 0; p < PP; p++) sum += lds[t*101 + p] * inv[p];
      qv[q*64 + t] = sum * 0.01f;
    }
  }
}

// ---------------- kVb: sum 5 shots -> B2T(bf16) + vptA(bf16) + MM + psumP + ssqP ----------------
__global__ __launch_bounds__(256) void kVb(const float* __restrict__ vptS,
                                           unsigned short* __restrict__ B2T,
                                           unsigned short* __restrict__ vptA,
                                           float* __restrict__ MM,
                                           float* __restrict__ psumP,
                                           float* __restrict__ ssqP){
  __shared__ float l2[256];
  __shared__ float wssq[4];
  int b = blockIdx.x;
  int pair = b / 25, jc = b - pair*25;
  int n = pair / PRJ, v = pair - n*PRJ;
  int j0 = jc * 256;
  int t = threadIdx.x;
  int j = j0 + t;
  float s = 0.f;
  #pragma unroll
  for (int k = 0; k < KSHOT; k++){
    int sk = (n*KSHOT + k)*PRJ + v;
    s += vptS[(size_t)sk*6400 + j];
  }
  float val = s * 0.2f;
  int plocal = (j >> 6) & 3;
  int d = j & 63;
  l2[d*4 + plocal] = val;
  float sq = redsum64(val*val);
  if ((t & 63) == 0) wssq[t >> 6] = sq;
  __syncthreads();
  if (t < 64){
    int p0 = j0 >> 6;
    float4 w4 = make_float4(l2[t*4+0], l2[t*4+1], l2[t*4+2], l2[t*4+3]);
    ushort4 h;
    h.x = bfr(w4.x); h.y = bfr(w4.y); h.z = bfr(w4.z); h.w = bfr(w4.w);
    *(ushort4*)(B2T + (size_t)pair*6400 + t*100 + p0) = h;
    // vptA[n][d][v*128 + p] bf16 (k-padded view blocks)
    unsigned short* va = vptA + ((size_t)(n*64 + t))*1792 + v*128;
    *(ushort4*)(va + p0) = h;
    if (jc == 24){
      #pragma unroll
      for (int z = 0; z < 7; z++)
        *(ushort4*)(va + 100 + z*4) = make_ushort4(0,0,0,0);
    }
    psumP[((size_t)pair*25 + jc)*64 + t] = w4.x + w4.y + w4.z + w4.w;
  }
  if (t >= 128 && t < 132){
    int i = t - 128;
    float m = 0.f;
    #pragma unroll
    for (int dd2 = 0; dd2 < 64; dd2++) m += l2[dd2*4 + i];
    MM[pair*100 + (j0 >> 6) + i] = m * (1.f/64.f);
  }
  if (t == 192)
    ssqP[pair*25 + jc] = wssq[0] + wssq[1] + wssq[2] + wssq[3];
}

// ---------------- kVc2: reduce chunk partials -> psum + vninv ----------------
__global__ __launch_bounds__(64) void kVc2(const float* __restrict__ psumP,
                                           const float* __restrict__ ssqP,
                                           float* __restrict__ psum,
                                           float* __restrict__ vninv){
  int pair = blockIdx.x, l = threadIdx.x;
  float s = 0.f;
  #pragma unroll
  for (int c = 0; c < 25; c++) s += psumP[((size_t)pair*25 + c)*64 + l];
  psum[pair*64 + l] = s;
  float sq = (l < 25) ? ssqP[pair*25 + l] : 0.f;
  float tot = redsum64(sq);
  if (l == 0) vninv[pair] = 1.f / fmaxf(sqrtf(tot), 1e-12f);
}

// ---------------- kS: pure MFMA, no LDS, K-chunk 256 ----------------
__global__ __launch_bounds__(256) void kS(const unsigned short* __restrict__ fqb,
                                          const unsigned short* __restrict__ B2T,
                                          float* __restrict__ sim32){
  int b = blockIdx.x;
  int fg = b % FGROUPS, mg = b / FGROUPS;
  int t = threadIdx.x;
  int l = t & 63;
  int wu = __builtin_amdgcn_readfirstlane(t >> 6);
  int q0 = mg*64 + wu*16;
  int fbase = fg * KCH;

  int lr = l & 15;
  int kb = l >> 4;

  f32x4 acc0 = {0.f,0.f,0.f,0.f};
  f32x4 acc1 = {0.f,0.f,0.f,0.f};
  f32x4 acc2 = {0.f,0.f,0.f,0.f};
  f32x4 acc3 = {0.f,0.f,0.f,0.f};
  f32x4 acc4 = {0.f,0.f,0.f,0.f};

  const unsigned short* Ab = fqb + (size_t)(q0 + lr)*6400 + fbase + kb*8;
  const unsigned short* Bb = B2T + (size_t)lr*6400 + fbase + kb*8;
  bool ok4 = (64 + lr) < NPAIR;

  #pragma unroll
  for (int s = 0; s < 8; s++){
    short8 a = *(const short8*)(Ab + s*32);
    short8 b0 = *(const short8*)(Bb + s*32);
    short8 b1 = *(const short8*)(Bb + 16*6400 + s*32);
    short8 b2 = *(const short8*)(Bb + 32*6400 + s*32);
    short8 b3 = *(const short8*)(Bb + 48*6400 + s*32);
    short8 b4 = ok4 ? *(const short8*)(Bb + (size_t)64*6400 + s*32) : (short8)(short)0;
    acc0 = __builtin_amdgcn_mfma_f32_16x16x32_bf16(a, b0, acc0, 0, 0, 0);
    acc1 = __builtin_amdgcn_mfma_f32_16x16x32_bf16(a, b1, acc1, 0, 0, 0);
    acc2 = __builtin_amdgcn_mfma_f32_16x16x32_bf16(a, b2, acc2, 0, 0, 0);
    acc3 = __builtin_amdgcn_mfma_f32_16x16x32_bf16(a, b3, acc3, 0, 0, 0);
    acc4 = __builtin_amdgcn_mfma_f32_16x16x32_bf16(a, b4, acc4, 0, 0, 0);
  }

  float* sp = sim32 + (size_t)fg*SIM_STRIDE + (size_t)(q0 + kb*4)*NPAIR;
  #pragma unroll
  for (int i = 0; i < 4; i++){
    sp[(size_t)i*NPAIR + lr]      = acc0[i];
    sp[(size_t)i*NPAIR + 16 + lr] = acc1[i];
    sp[(size_t)i*NPAIR + 32 + lr] = acc2[i];
    sp[(size_t)i*NPAIR + 48 + lr] = acc3[i];
    if (ok4) sp[(size_t)i*NPAIR + 64 + lr] = acc4[i];
  }
}

// ---------------- kM: sum 25 f-chunk partials + per-(q,n) softmax over 14 views ----------------
__global__ __launch_bounds__(256) void kM(const float* __restrict__ sim32,
                                          const float* __restrict__ vninv,
                                          const float* __restrict__ temp,
                                          float* __restrict__ pw){
  int t = blockIdx.x*256 + threadIdx.x;
  if (t >= NQ*NWAY) return;
  int q = t / NWAY, n = t - q*NWAY;
  float invT = 1.f / (temp[0] + 1e-6f);
  float s[PRJ];
  #pragma unroll
  for (int v = 0; v < PRJ; v++) s[v] = 0.f;
  for (int c = 0; c < FGROUPS; c++){
    const float* sp = sim32 + (size_t)c*SIM_STRIDE + q*NPAIR + n*PRJ;
    #pragma unroll
    for (int v = 0; v < PRJ; v++) s[v] += sp[v];
  }
  float m = -3.4e38f;
  #pragma unroll
  for (int v = 0; v < PRJ; v++){
    s[v] = s[v] * vninv[n*PRJ + v] * invT;
    m = fmaxf(m, s[v]);
  }
  float sum = 0.f;
  #pragma unroll
  for (int v = 0; v < PRJ; v++){ s[v] = expf(s[v] - m); sum += s[v]; }
  float rs = 1.f / sum;
  #pragma unroll
  for (int v = 0; v < PRJ; v++) pw[q*NPAIR + n*PRJ + v] = s[v] * rs;
}

// ---------------- kSg: sg[q][n][128] = sigmoid(sum_v pw*MM), zero pad p>=100 ----------------
__global__ __launch_bounds__(256) void kSg(const float* __restrict__ pw,
                                           const float* __restrict__ MM,
                                           float* __restrict__ sg){
  __shared__ float pwl[70];
  int q = blockIdx.x, t = threadIdx.x;
  if (t < NPAIR) pwl[t] = pw[q*NPAIR + t];
  __syncthreads();
  for (int i = t; i < NWAY*128; i += 256){
    int n = i >> 7, p = i & 127;
    float val = 0.f;
    if (p < 100){
      float s = 0.f;
      #pragma unroll
      for (int v = 0; v < PRJ; v++)
        s += pwl[n*PRJ + v] * MM[(n*PRJ + v)*100 + p];
      val = 1.f / (1.f + expf(-s));
    }
    sg[(size_t)q*640 + i] = val;
  }
}

// ---------------- kG: proto_q via MFMA, A built in-register (pw*sg), K halves ----------------
__global__ __launch_bounds__(256) void kG(const float* __restrict__ sg,
                                          const float* __restrict__ pw,
                                          const unsigned short* __restrict__ vptA,
                                          float* __restrict__ pq2){
  int b = blockIdx.x;
  int kh = b & 1;
  int r = b >> 1;
  int n = r / 64, qg = r - n*64;
  int q0 = qg * 16;
  int t = threadIdx.x;
  int l = t & 63;
  int wu = __builtin_amdgcn_readfirstlane(t >> 6);
  int d0 = wu * 16;
  int lr = l & 15, kb = l >> 4;

  int q = q0 + lr;
  const float* sgp = sg + (size_t)q*640 + n*128 + kb*8;
  const unsigned short* Yb = vptA + ((size_t)(n*64 + d0 + lr))*1792 + kh*896 + kb*8;

  float pv[7];
  #pragma unroll
  for (int i = 0; i < 7; i++) pv[i] = pw[q*NPAIR + n*PRJ + kh*7 + i];

  f32x4 acc = {0.f,0.f,0.f,0.f};
  #pragma unroll 4
  for (int s = 0; s < 28; s++){
    int pidx = (s & 3) * 32;
    float4 g0 = *(const float4*)(sgp + pidx);
    float4 g1 = *(const float4*)(sgp + pidx + 4);
    float pwv = pv[s >> 2];
    short8 a;
    a[0] = (short)bfr(pwv * g0.x);
    a[1] = (short)bfr(pwv * g0.y);
    a[2] = (short)bfr(pwv * g0.z);
    a[3] = (short)bfr(pwv * g0.w);
    a[4] = (short)bfr(pwv * g1.x);
    a[5] = (short)bfr(pwv * g1.y);
    a[6] = (short)bfr(pwv * g1.z);
    a[7] = (short)bfr(pwv * g1.w);
    short8 y = *(const short8*)(Yb + s*32);
    acc = __builtin_amdgcn_mfma_f32_16x16x32_bf16(a, y, acc, 0, 0, 0);
  }
  #pragma unroll
  for (int i = 0; i < 4; i++)
    pq2[(size_t)kh*PQ_ELEMS + ((size_t)(q0 + kb*4 + i)*NWAY + n)*64 + d0 + lr] = acc[i];
}

// ---------------- kF: 5 waves per query, wave = n; pq2-sum and base fused in ----------------
__global__ __launch_bounds__(320) void kF(const float* __restrict__ qv,
                                          const float* __restrict__ pq2,
                                          const float* __restrict__ psum,
                                          const float* __restrict__ Wq,
                                          const float* __restrict__ bq,
                                          const float* __restrict__ Wk,
                                          const float* __restrict__ bk,
                                          const float* __restrict__ gate,
                                          const int*   __restrict__ label,
                                          float* __restrict__ pred,
                                          float* __restrict__ cls,
                                          float* __restrict__ aln){
  __shared__ float qvl[64];
  __shared__ float qp[16];
  __shared__ float scn[NWAY], cosn[NWAY], c2n[NWAY];
  __shared__ float dl5[NWAY][64];
  int q = blockIdx.x, t = threadIdx.x;
  int w = t >> 6, l = t & 63;      // w = n

  float qvv = qv[q*64 + l];
  float qss = redsum64(qvv*qvv);
  float qn8 = fmaxf(sqrtf(qss), 1e-8f);
  if (w == 0) qvl[l] = qvv;
  __syncthreads();
  if (w == 0 && l < 16){
    float s = bq[l];
    #pragma unroll
    for (int d = 0; d < 64; d++) s += qvl[d] * Wq[d*16 + l];
    qp[l] = s;
  }
  __syncthreads();

  float wkq = 0.f;
  #pragma unroll
  for (int e = 0; e < 16; e++) wkq += Wk[l*16 + e] * qp[e];
  float qpb = 0.f;
  #pragma unroll
  for (int e = 0; e < 16; e++) qpb += qp[e] * bk[e];

  size_t idx = (size_t)(q*NWAY + w)*64 + l;
  float x = pq2[idx] + pq2[(size_t)PQ_ELEMS + idx];

  float dq = redsum64(qvv * x);
  float ps = redsum64(x * x);
  float cosw = dq / (qn8 * fmaxf(sqrtf(ps), 1e-8f));
  float sd = redsum64(x * wkq);
  float scw = (sd + qpb) * 0.25f;
  if (l == 0){ scn[w] = scw; cosn[w] = cosw; }
  __syncthreads();

  float am = scn[0];
  #pragma unroll
  for (int n = 1; n < NWAY; n++) am = fmaxf(am, scn[n]);
  float asum = 0.f;
  #pragma unroll
  for (int n = 0; n < NWAY; n++) asum += expf(scn[n] - am);
  float attw = expf(scw - am) / asum;

  float g0 = gate[0], g1 = gate[1], g2 = gate[2];
  float gm = fmaxf(fmaxf(g0, g1), g2);
  float e0 = expf(g0 - gm), e1 = expf(g1 - gm), e2 = expf(g2 - gm);
  float gs = 1.f / (e0 + e1 + e2);
  float b0 = (e0 + e1 + e2) * gs;
  float b1 = (e1 + e2) * gs;
  float b2 = e2 * gs;

  float bs = 0.f;
  #pragma unroll
  for (int v = 0; v < PRJ; v++) bs += psum[(w*PRJ + v)*64 + l];
  bs *= (1.f/1400.f);

  float f  = x * attw;
  float dd = fabsf(f - bs);
  dl5[w][l] = dd;
  int rank = 0;
  #pragma unroll 8
  for (int j = 0; j < 64; j++){
    float dj = dl5[w][j];
    rank += (dj > dd) || (dj == dd && j < l);
  }
  float cw = (rank < 16) ? b0 : (rank < 32) ? b1 : (rank < 48) ? b2 : 0.f;
  float gl = f * cw;
  float gss = redsum64(gl * gl);
  float num = redsum64(qvv * gl);
  float c2w = num / (qn8 * fmaxf(sqrtf(gss), 1e-12f));
  if (l == 0) c2n[w] = c2w;
  __syncthreads();

  float mx = c2n[0];
  #pragma unroll
  for (int n = 1; n < NWAY; n++) mx = fmaxf(mx, c2n[n]);
  float psum2 = 0.f;
  #pragma unroll
  for (int n = 0; n < NWAY; n++) psum2 += expf(c2n[n] - mx);
  if (l == 0) pred[q*NWAY + w] = expf(c2w - mx) / psum2;

  if (t == 0){
    int lab = label[q];
    float lm = LAMDA * mx;
    float lsum = 0.f;
    #pragma unroll
    for (int n = 0; n < NWAY; n++) lsum += expf(LAMDA * c2n[n] - lm);
    float c2l = c2n[lab], cosl = cosn[lab];
    float clsv = (lm + logf(lsum)) - LAMDA * c2l;
    float sum5 = 0.f, minn = 3.4e38f;
    #pragma unroll
    for (int n = 0; n < NWAY; n++){
      sum5 += cosn[n];
      if (n != lab) minn = fminf(minn, cosn[n]);
    }
    float hn = (sum5 - cosl - minn) * (1.f/3.f);
    float al = fmaxf(hn - cosl + MARGIN, 0.f);
    cls[q] = clsv; aln[q] = al;
  }
}

// ---------------- kL: loss reduction ----------------
__global__ __launch_bounds__(256) void kL(const float* __restrict__ cls,
                                          const float* __restrict__ aln,
                                          float* __restrict__ out){
  __shared__ float r1[256], r2[256];
  int t = threadIdx.x;
  float s1 = 0.f, s2 = 0.f;
  for (int i = t; i < NQ; i += 256){ s1 += cls[i]; s2 += aln[i]; }
  r1[t] = s1; r2[t] = s2;
  __syncthreads();
  for (int o = 128; o > 0; o >>= 1){
    if (t < o){ r1[t] += r1[t + o]; r2[t] += r2[t + o]; }
    __syncthreads();
  }
  if (t == 0)
    out[NQ*NWAY] = r1[0]*(1.f/NQ) + 0.3f*(r2[0]*(1.f/NQ));
}

extern "C" void kernel_launch(void* const* d_in, const int* in_sizes, int n_in,
                              void* d_out, int out_size, void* d_ws, size_t ws_size,
                              hipStream_t stream){
  const float* feat = (const float*)d_in[0];
  const float* temp = (const float*)d_in[1];
  const float* gate = (const float*)d_in[2];
  const float* Wq   = (const float*)d_in[3];
  const float* bq   = (const float*)d_in[4];
  const float* Wk   = (const float*)d_in[5];
  const float* bk   = (const float*)d_in[6];
  const int*   lab  = (const int*)d_in[7];
  float* out = (float*)d_out;
  float* ws  = (float*)d_ws;

  float* vptS  = ws + VPTS_OFF;
  unsigned short* B2T = (unsigned short*)(ws + B2T_OFF);
  float* MMp   = ws + MM_OFF;
  float* vninv = ws + VNINV_OFF;
  float* psum  = ws + PSUM_OFF;
  float* qv    = ws + QV_OFF;
  float* sim32 = ws + SIM32_OFF;
  float* pw    = ws + PW_OFF;
  float* pq2   = ws + PQ2_OFF;
  float* cls   = ws + CLS_OFF;
  float* aln   = ws + ALN_OFF;
  float* psumP = ws + PSUMP_OFF;
  float* ssqP  = ws + SSQP_OFF;
  unsigned short* fqb  = (unsigned short*)(ws + FQBF_OFF);
  unsigned short* vptA = (unsigned short*)(ws + VPTA_OFF);
  float* sg    = ws + SG_OFF;

  hipLaunchKernelGGL(kN, dim3(NS + NQ), dim3(256), 0, stream, feat, vptS, qv, fqb);
  hipLaunchKernelGGL(kVb, dim3(NPAIR*25), dim3(256), 0, stream, vptS, B2T, vptA, MMp, psumP, ssqP);
  hipLaunchKernelGGL(kVc2, dim3(NPAIR), dim3(64), 0, stream, psumP, ssqP, psum, vninv);
  hipLaunchKernelGGL(kS, dim3(16*FGROUPS), dim3(256), 0, stream, fqb, B2T, sim32);
  hipLaunchKernelGGL(kM, dim3((NQ*NWAY + 255)/256), dim3(256), 0, stream, sim32, vninv, temp, pw);
  hipLaunchKernelGGL(kSg, dim3(NQ), dim3(256), 0, stream, pw, MMp, sg);
  hipLaunchKernelGGL(kG, dim3(640), dim3(256), 0, stream, sg, pw, vptA, pq2);
  hipLaunchKernelGGL(kF, dim3(NQ), dim3(320), 0, stream, qv, pq2, psum, Wq, bq, Wk, bk, gate, lab, out, cls, aln);
  hipLaunchKernelGGL(kL, dim3(1), dim3(256), 0, stream, cls, aln, out);
}

// Round 20
// 76.231 us; speedup vs baseline: 1.0450x; 1.0450x over previous
//
#include <hip/hip_runtime.h>
#include <math.h>

#define NWAY 5
#define KSHOT 5
#define PRJ 14
#define DD 64
#define PP 100
#define NQ 1024
#define NS 350
#define NPAIR 70
#define LAMDA 32.0f
#define MARGIN 0.3f
#define FGROUPS 25
#define KCH 256

// ---- workspace layout (floats) ----
#define VPTS_OFF  448000     // [350][6400] = 2240000 ([p][d] layout)
#define B2T_OFF   2688000    // bf16 [70][6400]
#define MM_OFF    3136000    // [70][100]
#define VNINV_OFF 3143000    // [70] pad 128
#define PSUM_OFF  3143128    // [70][64]
#define QV_OFF    3147608    // [1024][64]
#define SIM32_OFF 3315544    // [25][1024][70] = 1792000
#define PW_OFF    7903064    // [1024][70]
#define PQ2_OFF   7974744    // [2][1024][5][64] = 655360
#define CLS_OFF   9285464    // [1024]
#define ALN_OFF   9286488    // [1024]
#define PSUMP_OFF 9287512    // [70][25][64]
#define SSQP_OFF  9399512    // [70][25]
#define FQBF_OFF  9401344    // bf16 [1024][6400] = 3276800 floats
#define VPTA_OFF  12678144   // bf16 [5][64][1792] = 286720 floats

#define PQ_ELEMS (NQ*NWAY*64)
#define SIM_STRIDE (NQ*NPAIR)

typedef __attribute__((ext_vector_type(8))) short short8;
typedef __attribute__((ext_vector_type(4))) float f32x4;

__device__ __forceinline__ float redsum64(float x){
  #pragma unroll
  for (int o = 1; o < 64; o <<= 1) x += __shfl_xor(x, o, 64);
  return x;
}

// f32 -> bf16 (RNE) bit pack
__device__ __forceinline__ unsigned short bfr(float x){
  unsigned int u = __float_as_uint(x);
  unsigned int r = (u + 0x7FFFu + ((u >> 16) & 1u)) >> 16;
  return (unsigned short)r;
}

// ---------------- kN: per-sample normalize; support -> vptS, query -> fqb(bf16)+qv ----------------
__global__ __launch_bounds__(256) void kN(const float* __restrict__ feat,
                                          float* __restrict__ vptS,
                                          float* __restrict__ qv,
                                          unsigned short* __restrict__ fqb){
  __shared__ float lds[64*101];
  __shared__ float inv[100];
  int s = blockIdx.x, t = threadIdx.x;
  const float* fp = feat + (size_t)s * 6400;
  #pragma unroll
  for (int i = 0; i < 25; i++){
    int j = t + 256*i;
    int d = j / 100, p = j - d*100;
    lds[d*101 + p] = fp[j];
  }
  __syncthreads();
  if (t < 100){
    float ss = 0.f;
    #pragma unroll
    for (int d = 0; d < 64; d++){ float x = lds[d*101 + t]; ss += x*x; }
    inv[t] = 1.f / fmaxf(sqrtf(ss), 1e-12f);
  }
  __syncthreads();
  if (s < NS){
    #pragma unroll
    for (int i = 0; i < 25; i++){
      int j = t + 256*i;
      int p = j >> 6, d = j & 63;
      vptS[(size_t)s*6400 + j] = lds[d*101 + p] * inv[p];
    }
  } else {
    int q = s - NS;
    #pragma unroll
    for (int i = 0; i < 25; i++){
      int j = t + 256*i;
      int d = j / 100, p = j - d*100;
      fqb[(size_t)q*6400 + j] = bfr(lds[d*101 + p] * inv[p]);
    }
    if (t < 64){
      float sum = 0.f;
      for (int p = 0; p < PP; p++) sum += lds[t*101 + p] * inv[p];
      qv[q*64 + t] = sum * 0.01f;
    }
  }
}

// ---------------- kVb: sum 5 shots -> B2T(bf16) + vptA(bf16) + MM + psumP + ssqP ----------------
__global__ __launch_bounds__(256) void kVb(const float* __restrict__ vptS,
                                           unsigned short* __restrict__ B2T,
                                           unsigned short* __restrict__ vptA,
                                           float* __restrict__ MM,
                                           float* __restrict__ psumP,
                                           float* __restrict__ ssqP){
  __shared__ float l2[256];
  __shared__ float wssq[4];
  int b = blockIdx.x;
  int pair = b / 25, jc = b - pair*25;
  int n = pair / PRJ, v = pair - n*PRJ;
  int j0 = jc * 256;
  int t = threadIdx.x;
  int j = j0 + t;
  float s = 0.f;
  #pragma unroll
  for (int k = 0; k < KSHOT; k++){
    int sk = (n*KSHOT + k)*PRJ + v;
    s += vptS[(size_t)sk*6400 + j];
  }
  float val = s * 0.2f;
  int plocal = (j >> 6) & 3;
  int d = j & 63;
  l2[d*4 + plocal] = val;
  float sq = redsum64(val*val);
  if ((t & 63) == 0) wssq[t >> 6] = sq;
  __syncthreads();
  if (t < 64){
    int p0 = j0 >> 6;
    float4 w4 = make_float4(l2[t*4+0], l2[t*4+1], l2[t*4+2], l2[t*4+3]);
    ushort4 h;
    h.x = bfr(w4.x); h.y = bfr(w4.y); h.z = bfr(w4.z); h.w = bfr(w4.w);
    *(ushort4*)(B2T + (size_t)pair*6400 + t*100 + p0) = h;
    unsigned short* va = vptA + ((size_t)(n*64 + t))*1792 + v*128;
    *(ushort4*)(va + p0) = h;
    if (jc == 24){
      #pragma unroll
      for (int z = 0; z < 7; z++)
        *(ushort4*)(va + 100 + z*4) = make_ushort4(0,0,0,0);
    }
    psumP[((size_t)pair*25 + jc)*64 + t] = w4.x + w4.y + w4.z + w4.w;
  }
  if (t >= 128 && t < 132){
    int i = t - 128;
    float m = 0.f;
    #pragma unroll
    for (int dd2 = 0; dd2 < 64; dd2++) m += l2[dd2*4 + i];
    MM[pair*100 + (j0 >> 6) + i] = m * (1.f/64.f);
  }
  if (t == 192)
    ssqP[pair*25 + jc] = wssq[0] + wssq[1] + wssq[2] + wssq[3];
}

// ---------------- kVc2: reduce chunk partials -> psum + vninv ----------------
__global__ __launch_bounds__(64) void kVc2(const float* __restrict__ psumP,
                                           const float* __restrict__ ssqP,
                                           float* __restrict__ psum,
                                           float* __restrict__ vninv){
  int pair = blockIdx.x, l = threadIdx.x;
  float s = 0.f;
  #pragma unroll
  for (int c = 0; c < 25; c++) s += psumP[((size_t)pair*25 + c)*64 + l];
  psum[pair*64 + l] = s;
  float sq = (l < 25) ? ssqP[pair*25 + l] : 0.f;
  float tot = redsum64(sq);
  if (l == 0) vninv[pair] = 1.f / fmaxf(sqrtf(tot), 1e-12f);
}

// ---------------- kS: pure MFMA, no LDS, K-chunk 256 ----------------
__global__ __launch_bounds__(256) void kS(const unsigned short* __restrict__ fqb,
                                          const unsigned short* __restrict__ B2T,
                                          float* __restrict__ sim32){
  int b = blockIdx.x;
  int fg = b % FGROUPS, mg = b / FGROUPS;
  int t = threadIdx.x;
  int l = t & 63;
  int wu = __builtin_amdgcn_readfirstlane(t >> 6);
  int q0 = mg*64 + wu*16;
  int fbase = fg * KCH;

  int lr = l & 15;
  int kb = l >> 4;

  f32x4 acc0 = {0.f,0.f,0.f,0.f};
  f32x4 acc1 = {0.f,0.f,0.f,0.f};
  f32x4 acc2 = {0.f,0.f,0.f,0.f};
  f32x4 acc3 = {0.f,0.f,0.f,0.f};
  f32x4 acc4 = {0.f,0.f,0.f,0.f};

  const unsigned short* Ab = fqb + (size_t)(q0 + lr)*6400 + fbase + kb*8;
  const unsigned short* Bb = B2T + (size_t)lr*6400 + fbase + kb*8;
  bool ok4 = (64 + lr) < NPAIR;

  #pragma unroll
  for (int s = 0; s < 8; s++){
    short8 a = *(const short8*)(Ab + s*32);
    short8 b0 = *(const short8*)(Bb + s*32);
    short8 b1 = *(const short8*)(Bb + 16*6400 + s*32);
    short8 b2 = *(const short8*)(Bb + 32*6400 + s*32);
    short8 b3 = *(const short8*)(Bb + 48*6400 + s*32);
    short8 b4 = ok4 ? *(const short8*)(Bb + (size_t)64*6400 + s*32) : (short8)(short)0;
    acc0 = __builtin_amdgcn_mfma_f32_16x16x32_bf16(a, b0, acc0, 0, 0, 0);
    acc1 = __builtin_amdgcn_mfma_f32_16x16x32_bf16(a, b1, acc1, 0, 0, 0);
    acc2 = __builtin_amdgcn_mfma_f32_16x16x32_bf16(a, b2, acc2, 0, 0, 0);
    acc3 = __builtin_amdgcn_mfma_f32_16x16x32_bf16(a, b3, acc3, 0, 0, 0);
    acc4 = __builtin_amdgcn_mfma_f32_16x16x32_bf16(a, b4, acc4, 0, 0, 0);
  }

  float* sp = sim32 + (size_t)fg*SIM_STRIDE + (size_t)(q0 + kb*4)*NPAIR;
  #pragma unroll
  for (int i = 0; i < 4; i++){
    sp[(size_t)i*NPAIR + lr]      = acc0[i];
    sp[(size_t)i*NPAIR + 16 + lr] = acc1[i];
    sp[(size_t)i*NPAIR + 32 + lr] = acc2[i];
    sp[(size_t)i*NPAIR + 48 + lr] = acc3[i];
    if (ok4) sp[(size_t)i*NPAIR + 64 + lr] = acc4[i];
  }
}

// ---------------- kM: sum 25 f-chunk partials + per-(q,n) softmax over 14 views ----------------
__global__ __launch_bounds__(256) void kM(const float* __restrict__ sim32,
                                          const float* __restrict__ vninv,
                                          const float* __restrict__ temp,
                                          float* __restrict__ pw){
  int t = blockIdx.x*256 + threadIdx.x;
  if (t >= NQ*NWAY) return;
  int q = t / NWAY, n = t - q*NWAY;
  float invT = 1.f / (temp[0] + 1e-6f);
  float s[PRJ];
  #pragma unroll
  for (int v = 0; v < PRJ; v++) s[v] = 0.f;
  for (int c = 0; c < FGROUPS; c++){
    const float* sp = sim32 + (size_t)c*SIM_STRIDE + q*NPAIR + n*PRJ;
    #pragma unroll
    for (int v = 0; v < PRJ; v++) s[v] += sp[v];
  }
  float m = -3.4e38f;
  #pragma unroll
  for (int v = 0; v < PRJ; v++){
    s[v] = s[v] * vninv[n*PRJ + v] * invT;
    m = fmaxf(m, s[v]);
  }
  float sum = 0.f;
  #pragma unroll
  for (int v = 0; v < PRJ; v++){ s[v] = expf(s[v] - m); sum += s[v]; }
  float rs = 1.f / sum;
  #pragma unroll
  for (int v = 0; v < PRJ; v++) pw[q*NPAIR + n*PRJ + v] = s[v] * rs;
}

// ---------------- kG v2: proto_q via MFMA, sg computed in LDS (kSg fused) ----------------
// grid 640: kh = b&1 (7 views each), r = b>>1: n = r/64, qg = r%64 (16 q). 4 waves = 16-d tiles.
__global__ __launch_bounds__(256) void kG(const float* __restrict__ pw,
                                          const float* __restrict__ MM,
                                          const unsigned short* __restrict__ vptA,
                                          float* __restrict__ pq2){
  __shared__ float sgl[16*132];   // [ql][p], pad 132 -> bank stride 4 per ql (2-way max)
  __shared__ float pwl[16*14];
  int b = blockIdx.x;
  int kh = b & 1;
  int r = b >> 1;
  int n = r / 64, qg = r - n*64;
  int q0 = qg * 16;
  int t = threadIdx.x;
  int l = t & 63;
  int wu = __builtin_amdgcn_readfirstlane(t >> 6);
  int d0 = wu * 16;
  int lr = l & 15, kb = l >> 4;

  // preload pw rows for this block's 16 queries x 14 views (of class n)
  if (t < 224){
    int ql = t / 14, v = t - ql*14;
    pwl[ql*14 + v] = pw[(q0 + ql)*NPAIR + n*PRJ + v];
  }
  __syncthreads();
  // compute sg slice: sigmoid(sum_v pw*MM) for 16 q x 128 p (p>=100 -> 0)
  for (int i = t; i < 16*128; i += 256){
    int ql = i >> 7, p = i & 127;
    float val = 0.f;
    if (p < 100){
      float s = 0.f;
      #pragma unroll
      for (int v = 0; v < PRJ; v++)
        s += pwl[ql*14 + v] * MM[(n*PRJ + v)*100 + p];
      val = 1.f / (1.f + expf(-s));
    }
    sgl[ql*132 + p] = val;
  }
  __syncthreads();

  const float* sgp = sgl + lr*132 + kb*8;
  const unsigned short* Yb = vptA + ((size_t)(n*64 + d0 + lr))*1792 + kh*896 + kb*8;

  float pv[7];
  #pragma unroll
  for (int i = 0; i < 7; i++) pv[i] = pwl[lr*14 + kh*7 + i];

  f32x4 acc = {0.f,0.f,0.f,0.f};
  #pragma unroll 4
  for (int s = 0; s < 28; s++){
    int pidx = (s & 3) * 32;
    float4 g0 = *(const float4*)(sgp + pidx);
    float4 g1 = *(const float4*)(sgp + pidx + 4);
    float pwv = pv[s >> 2];
    short8 a;
    a[0] = (short)bfr(pwv * g0.x);
    a[1] = (short)bfr(pwv * g0.y);
    a[2] = (short)bfr(pwv * g0.z);
    a[3] = (short)bfr(pwv * g0.w);
    a[4] = (short)bfr(pwv * g1.x);
    a[5] = (short)bfr(pwv * g1.y);
    a[6] = (short)bfr(pwv * g1.z);
    a[7] = (short)bfr(pwv * g1.w);
    short8 y = *(const short8*)(Yb + s*32);
    acc = __builtin_amdgcn_mfma_f32_16x16x32_bf16(a, y, acc, 0, 0, 0);
  }
  #pragma unroll
  for (int i = 0; i < 4; i++)
    pq2[(size_t)kh*PQ_ELEMS + ((size_t)(q0 + kb*4 + i)*NWAY + n)*64 + d0 + lr] = acc[i];
}

// ---------------- kF: 5 waves per query, wave = n; pq2-sum and base fused in ----------------
__global__ __launch_bounds__(320) void kF(const float* __restrict__ qv,
                                          const float* __restrict__ pq2,
                                          const float* __restrict__ psum,
                                          const float* __restrict__ Wq,
                                          const float* __restrict__ bq,
                                          const float* __restrict__ Wk,
                                          const float* __restrict__ bk,
                                          const float* __restrict__ gate,
                                          const int*   __restrict__ label,
                                          float* __restrict__ pred,
                                          float* __restrict__ cls,
                                          float* __restrict__ aln){
  __shared__ float qvl[64];
  __shared__ float qp[16];
  __shared__ float scn[NWAY], cosn[NWAY], c2n[NWAY];
  __shared__ float dl5[NWAY][64];
  int q = blockIdx.x, t = threadIdx.x;
  int w = t >> 6, l = t & 63;      // w = n

  float qvv = qv[q*64 + l];
  float qss = redsum64(qvv*qvv);
  float qn8 = fmaxf(sqrtf(qss), 1e-8f);
  if (w == 0) qvl[l] = qvv;
  __syncthreads();
  if (w == 0 && l < 16){
    float s = bq[l];
    #pragma unroll
    for (int d = 0; d < 64; d++) s += qvl[d] * Wq[d*16 + l];
    qp[l] = s;
  }
  __syncthreads();

  float wkq = 0.f;
  #pragma unroll
  for (int e = 0; e < 16; e++) wkq += Wk[l*16 + e] * qp[e];
  float qpb = 0.f;
  #pragma unroll
  for (int e = 0; e < 16; e++) qpb += qp[e] * bk[e];

  size_t idx = (size_t)(q*NWAY + w)*64 + l;
  float x = pq2[idx] + pq2[(size_t)PQ_ELEMS + idx];

  float dq = redsum64(qvv * x);
  float ps = redsum64(x * x);
  float cosw = dq / (qn8 * fmaxf(sqrtf(ps), 1e-8f));
  float sd = redsum64(x * wkq);
  float scw = (sd + qpb) * 0.25f;
  if (l == 0){ scn[w] = scw; cosn[w] = cosw; }
  __syncthreads();

  float am = scn[0];
  #pragma unroll
  for (int n = 1; n < NWAY; n++) am = fmaxf(am, scn[n]);
  float asum = 0.f;
  #pragma unroll
  for (int n = 0; n < NWAY; n++) asum += expf(scn[n] - am);
  float attw = expf(scw - am) / asum;

  float g0 = gate[0], g1 = gate[1], g2 = gate[2];
  float gm = fmaxf(fmaxf(g0, g1), g2);
  float e0 = expf(g0 - gm), e1 = expf(g1 - gm), e2 = expf(g2 - gm);
  float gs = 1.f / (e0 + e1 + e2);
  float b0 = (e0 + e1 + e2) * gs;
  float b1 = (e1 + e2) * gs;
  float b2 = e2 * gs;

  float bs = 0.f;
  #pragma unroll
  for (int v = 0; v < PRJ; v++) bs += psum[(w*PRJ + v)*64 + l];
  bs *= (1.f/1400.f);

  float f  = x * attw;
  float dd = fabsf(f - bs);
  dl5[w][l] = dd;
  int rank = 0;
  #pragma unroll 8
  for (int j = 0; j < 64; j++){
    float dj = dl5[w][j];
    rank += (dj > dd) || (dj == dd && j < l);
  }
  float cw = (rank < 16) ? b0 : (rank < 32) ? b1 : (rank < 48) ? b2 : 0.f;
  float gl = f * cw;
  float gss = redsum64(gl * gl);
  float num = redsum64(qvv * gl);
  float c2w = num / (qn8 * fmaxf(sqrtf(gss), 1e-12f));
  if (l == 0) c2n[w] = c2w;
  __syncthreads();

  float mx = c2n[0];
  #pragma unroll
  for (int n = 1; n < NWAY; n++) mx = fmaxf(mx, c2n[n]);
  float psum2 = 0.f;
  #pragma unroll
  for (int n = 0; n < NWAY; n++) psum2 += expf(c2n[n] - mx);
  if (l == 0) pred[q*NWAY + w] = expf(c2w - mx) / psum2;

  if (t == 0){
    int lab = label[q];
    float lm = LAMDA * mx;
    float lsum = 0.f;
    #pragma unroll
    for (int n = 0; n < NWAY; n++) lsum += expf(LAMDA * c2n[n] - lm);
    float c2l = c2n[lab], cosl = cosn[lab];
    float clsv = (lm + logf(lsum)) - LAMDA * c2l;
    float sum5 = 0.f, minn = 3.4e38f;
    #pragma unroll
    for (int n = 0; n < NWAY; n++){
      sum5 += cosn[n];
      if (n != lab) minn = fminf(minn, cosn[n]);
    }
    float hn = (sum5 - cosl - minn) * (1.f/3.f);
    float al = fmaxf(hn - cosl + MARGIN, 0.f);
    cls[q] = clsv; aln[q] = al;
  }
}

// ---------------- kL: loss reduction ----------------
__global__ __launch_bounds__(256) void kL(const float* __restrict__ cls,
                                          const float* __restrict__ aln,
                                          float* __restrict__ out){
  __shared__ float r1[256], r2[256];
  int t = threadIdx.x;
  float s1 = 0.f, s2 = 0.f;
  for (int i = t; i < NQ; i += 256){ s1 += cls[i]; s2 += aln[i]; }
  r1[t] = s1; r2[t] = s2;
  __syncthreads();
  for (int o = 128; o > 0; o >>= 1){
    if (t < o){ r1[t] += r1[t + o]; r2[t] += r2[t + o]; }
    __syncthreads();
  }
  if (t == 0)
    out[NQ*NWAY] = r1[0]*(1.f/NQ) + 0.3f*(r2[0]*(1.f/NQ));
}

extern "C" void kernel_launch(void* const* d_in, const int* in_sizes, int n_in,
                              void* d_out, int out_size, void* d_ws, size_t ws_size,
                              hipStream_t stream){
  const float* feat = (const float*)d_in[0];
  const float* temp = (const float*)d_in[1];
  const float* gate = (const float*)d_in[2];
  const float* Wq   = (const float*)d_in[3];
  const float* bq   = (const float*)d_in[4];
  const float* Wk   = (const float*)d_in[5];
  const float* bk   = (const float*)d_in[6];
  const int*   lab  = (const int*)d_in[7];
  float* out = (float*)d_out;
  float* ws  = (float*)d_ws;

  float* vptS  = ws + VPTS_OFF;
  unsigned short* B2T = (unsigned short*)(ws + B2T_OFF);
  float* MMp   = ws + MM_OFF;
  float* vninv = ws + VNINV_OFF;
  float* psum  = ws + PSUM_OFF;
  float* qv    = ws + QV_OFF;
  float* sim32 = ws + SIM32_OFF;
  float* pw    = ws + PW_OFF;
  float* pq2   = ws + PQ2_OFF;
  float* cls   = ws + CLS_OFF;
  float* aln   = ws + ALN_OFF;
  float* psumP = ws + PSUMP_OFF;
  float* ssqP  = ws + SSQP_OFF;
  unsigned short* fqb  = (unsigned short*)(ws + FQBF_OFF);
  unsigned short* vptA = (unsigned short*)(ws + VPTA_OFF);

  hipLaunchKernelGGL(kN, dim3(NS + NQ), dim3(256), 0, stream, feat, vptS, qv, fqb);
  hipLaunchKernelGGL(kVb, dim3(NPAIR*25), dim3(256), 0, stream, vptS, B2T, vptA, MMp, psumP, ssqP);
  hipLaunchKernelGGL(kVc2, dim3(NPAIR), dim3(64), 0, stream, psumP, ssqP, psum, vninv);
  hipLaunchKernelGGL(kS, dim3(16*FGROUPS), dim3(256), 0, stream, fqb, B2T, sim32);
  hipLaunchKernelGGL(kM, dim3((NQ*NWAY + 255)/256), dim3(256), 0, stream, sim32, vninv, temp, pw);
  hipLaunchKernelGGL(kG, dim3(640), dim3(256), 0, stream, pw, MMp, vptA, pq2);
  hipLaunchKernelGGL(kF, dim3(NQ), dim3(320), 0, stream, qv, pq2, psum, Wq, bq, Wk, bk, gate, lab, out, cls, aln);
  hipLaunchKernelGGL(kL, dim3(1), dim3(256), 0, stream, cls, aln, out);
}